// Round 8
// baseline (104.784 us; speedup 1.0000x reference)
//
#include <hip/hip_runtime.h>
#include <hip/hip_fp16.h>
#include <cstdint>

#define B_SZ   1024
#define N_IN   256
#define NLAY   8
#define M_SZ   4096
#define K_SZ   16
#define NCOLS  (N_IN + 1 + NLAY * M_SZ)   // 33025
#define SCALE  4.9f
#define TPB    1024

// -4.9 * log2(e): sigmoid(z) = 1 / (1 + 2^(C*acc))
#define NEG_SCALE_LOG2E  (-7.069205700355921f)

// ---------------------------------------------------------------------------
// Prologue: pack (idx, fp16(W)) into one u32.
//   high16 = index (max 28928 < 32768), low16 = fp16(W).
// idx in HIGH so the LDS index is a single v_lshrrev; w in LOW so
// v_fma_mix_f32 can consume it directly via op_sel (no extraction, no cvt).
// ---------------------------------------------------------------------------
__global__ void pack_kernel(const int* __restrict__ edge_idx,
                            const float* __restrict__ W,
                            uint32_t* __restrict__ packed, int n) {
    int i = blockIdx.x * blockDim.x + threadIdx.x;
    if (i < n) {
        uint32_t id = (uint32_t)edge_idx[i];
        __half h = __float2half_rn(W[i]);
        packed[i] = (id << 16) | (uint32_t)__half_as_ushort(h);
    }
}

// ---------------------------------------------------------------------------
// Main kernel: one block = 2 batch rows; full activation history as half2 in
// LDS (132,100 B; lo = row b0, hi = row b0+1).
//
// Per gather (PACKED path): lshr+lshl (addr), ds_read_b32, then TWO
// v_fma_mix_f32 — f32 acc += f16(val half) * f16(w) with op_sel choosing the
// val half and the low-half weight. 4 VALU + 1 LDS per gather vs ~8 + 1 for
// the cvt-based version; round-7 showed the kernel runs in a VALU/LDS
// interleave regime, so the VALU cut should expose the LDS pipe floor.
// ---------------------------------------------------------------------------
template <bool PACKED>
__global__ __launch_bounds__(TPB, 4)
void ffn_kernel(const float* __restrict__ x,
                const uint32_t* __restrict__ packed,
                const int* __restrict__ edge_idx,
                const float* __restrict__ W,
                float* __restrict__ out) {
    __shared__ uint32_t vals[NCOLS];

    const int tid = threadIdx.x;
    const int b0  = blockIdx.x * 2;
    const float* __restrict__ x0 = x + (size_t)b0 * N_IN;
    const float* __restrict__ x1 = x0 + N_IN;

    for (int j = tid; j <= N_IN; j += TPB) {
        float v0 = (j < N_IN) ? x0[j] : 1.0f;
        float v1 = (j < N_IN) ? x1[j] : 1.0f;
        __half2 h2 = __floats2half2_rn(v0, v1);
        vals[j] = *reinterpret_cast<uint32_t*>(&h2);
    }
    __syncthreads();

    const int base = N_IN + 1;
    for (int l = 0; l < NLAY; ++l) {
        for (int i = 0; i < M_SZ / TPB; ++i) {
            const int m = tid + i * TPB;
            float acc0 = 0.f, acc1 = 0.f;

            if (PACKED) {
                const uint4* p4 =
                    reinterpret_cast<const uint4*>(packed + (size_t)(l * M_SZ + m) * K_SZ);
                uint4 pw[4];
                #pragma unroll
                for (int j = 0; j < 4; ++j) pw[j] = p4[j];
                #pragma unroll
                for (int j = 0; j < 4; ++j) {
                    uint32_t words[4] = {pw[j].x, pw[j].y, pw[j].z, pw[j].w};
                    #pragma unroll
                    for (int q = 0; q < 4; ++q) {
                        uint32_t p = words[q];
                        uint32_t v = vals[p >> 16];
                        // acc0 += f16(v.lo) * f16(p.lo)
                        asm("v_fma_mix_f32 %0, %1, %2, %0 op_sel:[0,0,0] op_sel_hi:[1,1,0]"
                            : "+v"(acc0) : "v"(v), "v"(p));
                        // acc1 += f16(v.hi) * f16(p.lo)
                        asm("v_fma_mix_f32 %0, %1, %2, %0 op_sel:[1,0,0] op_sel_hi:[1,1,0]"
                            : "+v"(acc1) : "v"(v), "v"(p));
                    }
                }
            } else {
                const int4*   i4 = reinterpret_cast<const int4*>(edge_idx + (size_t)(l * M_SZ + m) * K_SZ);
                const float4* w4 = reinterpret_cast<const float4*>(W + (size_t)(l * M_SZ + m) * K_SZ);
                #pragma unroll
                for (int j = 0; j < 4; ++j) {
                    int4   ii = i4[j];
                    float4 ww = w4[j];
                    int   idxs[4] = {ii.x, ii.y, ii.z, ii.w};
                    float wts[4]  = {ww.x, ww.y, ww.z, ww.w};
                    #pragma unroll
                    for (int q = 0; q < 4; ++q) {
                        uint32_t v = vals[idxs[q]];
                        __half2 h2 = *reinterpret_cast<__half2*>(&v);
                        acc0 = fmaf(__low2float(h2), wts[q], acc0);
                        acc1 = fmaf(__high2float(h2), wts[q], acc1);
                    }
                }
            }

            // sigmoid(SCALE*acc) = 1 / (1 + 2^(-SCALE*log2e*acc))
            float e0 = __builtin_amdgcn_exp2f(NEG_SCALE_LOG2E * acc0);
            float e1 = __builtin_amdgcn_exp2f(NEG_SCALE_LOG2E * acc1);
            float s0 = __builtin_amdgcn_rcpf(1.0f + e0);
            float s1 = __builtin_amdgcn_rcpf(1.0f + e1);

            if (l < NLAY - 1) {
                __half2 h2 = __floats2half2_rn(s0, s1);
                vals[base + l * M_SZ + m] = *reinterpret_cast<uint32_t*>(&h2);
            } else {
                out[(size_t)b0 * M_SZ + m]       = s0;
                out[(size_t)(b0 + 1) * M_SZ + m] = s1;
            }
        }
        __syncthreads();
    }
}

extern "C" void kernel_launch(void* const* d_in, const int* in_sizes, int n_in,
                              void* d_out, int out_size, void* d_ws, size_t ws_size,
                              hipStream_t stream) {
    const float* x        = (const float*)d_in[0];
    const float* W        = (const float*)d_in[1];
    const int*   edge_idx = (const int*)d_in[2];
    float*       out      = (float*)d_out;

    const int n = NLAY * M_SZ * K_SZ;  // 524288 packed words = 2 MB
    if (ws_size >= (size_t)n * sizeof(uint32_t)) {
        uint32_t* packed = (uint32_t*)d_ws;
        pack_kernel<<<(n + 255) / 256, 256, 0, stream>>>(edge_idx, W, packed, n);
        ffn_kernel<true><<<B_SZ / 2, TPB, 0, stream>>>(x, packed, nullptr, nullptr, out);
    } else {
        ffn_kernel<false><<<B_SZ / 2, TPB, 0, stream>>>(x, nullptr, edge_idx, W, out);
    }
}

// Round 9
// 79.942 us; speedup vs baseline: 1.3108x; 1.3108x over previous
//
#include <hip/hip_runtime.h>
#include <hip/hip_fp16.h>
#include <cstdint>

#define B_SZ   1024
#define N_IN   256
#define NLAY   8
#define M_SZ   4096
#define K_SZ   16
// Max column ever READ is 257 + 7*4096 - 1 = 28928 (layer-7 output goes
// straight to global). Round up for alignment.
#define NCOLS_LDS 28932
#define SCALE  4.9f
#define TPB    1024

// -SCALE * log2(e): sigmoid(SCALE*a) = 1 / (1 + 2^(-SCALE*log2e*a))
#define NEG_SCALE_LOG2E  (-7.069205700355921f)

// ---------------------------------------------------------------------------
// Prologue: pack (idx, fp16(W)) into one u32 (R5 layout: idx low, w high).
// ---------------------------------------------------------------------------
__global__ void pack_kernel(const int* __restrict__ edge_idx,
                            const float* __restrict__ W,
                            uint32_t* __restrict__ packed, int n) {
    int i = blockIdx.x * blockDim.x + threadIdx.x;
    if (i < n) {
        uint32_t id = (uint32_t)edge_idx[i] & 0xFFFFu;
        __half h = __float2half_rn(W[i]);
        packed[i] = id | ((uint32_t)__half_as_ushort(h) << 16);
    }
}

// ---------------------------------------------------------------------------
// Main kernel: one block = 2 batch rows; activation history as half2 in LDS
// (115,728 B; lo = row b0, hi = row b0+1).
//
// R9 structure: R5's compiler-scheduled gather body (LLVM batches the 16
// ds_reads and fuses cvt+fma into v_fma_mix — the R8 inline-asm version
// serialized the LDS pipe, +26 us) + 2-deep software pipeline on the packed
// table loads: iteration t issues t+1's 64 B of global loads before consuming
// t's gathers, including across the layer barrier (global loads don't touch
// LDS, safe to hoist over __syncthreads). Sigmoid via exp2+rcp (R8-proven).
// ---------------------------------------------------------------------------
template <bool PACKED>
__global__ __launch_bounds__(TPB, 4)
void ffn_kernel(const float* __restrict__ x,
                const uint32_t* __restrict__ packed,
                const int* __restrict__ edge_idx,
                const float* __restrict__ W,
                float* __restrict__ out) {
    __shared__ uint32_t vals[NCOLS_LDS];

    const int tid = threadIdx.x;
    const int b0  = blockIdx.x * 2;
    const float* __restrict__ x0 = x + (size_t)b0 * N_IN;
    const float* __restrict__ x1 = x0 + N_IN;

    // Stage x rows (+ bias col at N_IN) as half2.
    for (int j = tid; j <= N_IN; j += TPB) {
        float v0 = (j < N_IN) ? x0[j] : 1.0f;
        float v1 = (j < N_IN) ? x1[j] : 1.0f;
        __half2 h2 = __floats2half2_rn(v0, v1);
        vals[j] = *reinterpret_cast<uint32_t*>(&h2);
    }

    const int base = N_IN + 1;

    if (PACKED) {
        // Load packed words for (layer l, sub-iter i) into 16 regs.
        auto ldpk = [&](uint32_t dst[16], int l, int i) {
            const int m = tid + i * TPB;
            const uint4* p4 =
                reinterpret_cast<const uint4*>(packed + ((size_t)l * M_SZ + m) * K_SZ);
            #pragma unroll
            for (int j = 0; j < 4; ++j) {
                uint4 v = p4[j];
                dst[4*j+0] = v.x; dst[4*j+1] = v.y; dst[4*j+2] = v.z; dst[4*j+3] = v.w;
            }
        };

        uint32_t cur[16], nxt[16];
        ldpk(cur, 0, 0);                 // prefetch t=0 before first barrier
        __syncthreads();

        for (int l = 0; l < NLAY; ++l) {
            #pragma unroll
            for (int i = 0; i < 4; ++i) {
                // Prefetch next iteration's packed words (next layer's i=0
                // when i==3). Global loads: safe across the layer barrier.
                if (i < 3) {
                    ldpk(nxt, l, i + 1);
                } else if (l < NLAY - 1) {
                    ldpk(nxt, l + 1, 0);
                }

                const int m = tid + i * TPB;
                float acc0 = 0.f, acc1 = 0.f;
                #pragma unroll
                for (int q = 0; q < 16; ++q) {
                    uint32_t p = cur[q];
                    uint32_t v = vals[p & 0xFFFFu];
                    __half2 vh = *reinterpret_cast<__half2*>(&v);
                    __half2 ph = *reinterpret_cast<__half2*>(&p);
                    float wf = __high2float(ph);
                    acc0 = fmaf(__low2float(vh),  wf, acc0);
                    acc1 = fmaf(__high2float(vh), wf, acc1);
                }

                float e0 = __builtin_amdgcn_exp2f(NEG_SCALE_LOG2E * acc0);
                float e1 = __builtin_amdgcn_exp2f(NEG_SCALE_LOG2E * acc1);
                float s0 = __builtin_amdgcn_rcpf(1.0f + e0);
                float s1 = __builtin_amdgcn_rcpf(1.0f + e1);

                if (l < NLAY - 1) {
                    __half2 h2 = __floats2half2_rn(s0, s1);
                    vals[base + l * M_SZ + m] = *reinterpret_cast<uint32_t*>(&h2);
                } else {
                    out[(size_t)b0 * M_SZ + m]       = s0;
                    out[(size_t)(b0 + 1) * M_SZ + m] = s1;
                }

                #pragma unroll
                for (int q = 0; q < 16; ++q) cur[q] = nxt[q];
            }
            __syncthreads();
        }
    } else {
        __syncthreads();
        for (int l = 0; l < NLAY; ++l) {
            for (int i = 0; i < M_SZ / TPB; ++i) {
                const int m = tid + i * TPB;
                float acc0 = 0.f, acc1 = 0.f;
                const int4*   i4 = reinterpret_cast<const int4*>(edge_idx + ((size_t)l * M_SZ + m) * K_SZ);
                const float4* w4 = reinterpret_cast<const float4*>(W + ((size_t)l * M_SZ + m) * K_SZ);
                #pragma unroll
                for (int j = 0; j < 4; ++j) {
                    int4   ii = i4[j];
                    float4 ww = w4[j];
                    int   idxs[4] = {ii.x, ii.y, ii.z, ii.w};
                    float wts[4]  = {ww.x, ww.y, ww.z, ww.w};
                    #pragma unroll
                    for (int q = 0; q < 4; ++q) {
                        uint32_t v = vals[idxs[q]];
                        __half2 h2 = *reinterpret_cast<__half2*>(&v);
                        acc0 = fmaf(__low2float(h2),  wts[q], acc0);
                        acc1 = fmaf(__high2float(h2), wts[q], acc1);
                    }
                }
                float e0 = __builtin_amdgcn_exp2f(NEG_SCALE_LOG2E * acc0);
                float e1 = __builtin_amdgcn_exp2f(NEG_SCALE_LOG2E * acc1);
                float s0 = __builtin_amdgcn_rcpf(1.0f + e0);
                float s1 = __builtin_amdgcn_rcpf(1.0f + e1);
                if (l < NLAY - 1) {
                    __half2 h2 = __floats2half2_rn(s0, s1);
                    vals[base + l * M_SZ + m] = *reinterpret_cast<uint32_t*>(&h2);
                } else {
                    out[(size_t)b0 * M_SZ + m]       = s0;
                    out[(size_t)(b0 + 1) * M_SZ + m] = s1;
                }
            }
            __syncthreads();
        }
    }
}

extern "C" void kernel_launch(void* const* d_in, const int* in_sizes, int n_in,
                              void* d_out, int out_size, void* d_ws, size_t ws_size,
                              hipStream_t stream) {
    const float* x        = (const float*)d_in[0];
    const float* W        = (const float*)d_in[1];
    const int*   edge_idx = (const int*)d_in[2];
    float*       out      = (float*)d_out;

    const int n = NLAY * M_SZ * K_SZ;  // 524288 packed words = 2 MB
    if (ws_size >= (size_t)n * sizeof(uint32_t)) {
        uint32_t* packed = (uint32_t*)d_ws;
        pack_kernel<<<(n + 255) / 256, 256, 0, stream>>>(edge_idx, W, packed, n);
        ffn_kernel<true><<<B_SZ / 2, TPB, 0, stream>>>(x, packed, nullptr, nullptr, out);
    } else {
        ffn_kernel<false><<<B_SZ / 2, TPB, 0, stream>>>(x, nullptr, edge_idx, W, out);
    }
}